// Round 1
// baseline (236.366 us; speedup 1.0000x reference)
//
#include <hip/hip_runtime.h>
#include <hip/hip_bf16.h>

#define B_NUM 4096
#define N_NUM 2048
#define E_NUM 1638
#define OUT_NUM 512
#define NTOT 2560  // N_NUM + OUT_NUM

typedef unsigned short u16;
typedef __attribute__((ext_vector_type(8))) __bf16 bf16x8;
typedef __attribute__((ext_vector_type(4))) float f32x4;

__device__ __forceinline__ u16 f2bf(float f) {
  union { float f; unsigned u; } v; v.f = f;
  unsigned r = v.u + 0x7fffu + ((v.u >> 16) & 1u);
  return (u16)(r >> 16);
}

__device__ __forceinline__ void gload_lds16(const u16* src, u16* dst) {
  __builtin_amdgcn_global_load_lds((__attribute__((address_space(1))) void*)src,
                                   (__attribute__((address_space(3))) void*)dst,
                                   16, 0, 0);
}

// ---------------- prep_u: u = relu(0.9*x + 0.1*(i + b)) ----------------
// writes exact f32 u into d_out's u region, and bf16 copy into ws for GEMM.
__global__ __launch_bounds__(256) void prep_u(const float* __restrict__ in_i,
                                              const float* __restrict__ in_x,
                                              const float* __restrict__ bias,
                                              float* __restrict__ u_f32,
                                              u16* __restrict__ u_bf16) {
  const int t = blockIdx.x * 256 + threadIdx.x;
  const int e = t * 4;
  const float4 iv = *(const float4*)(in_i + e);
  const float4 xv = *(const float4*)(in_x + e);
  const float4 bv = *(const float4*)(bias + (e & (N_NUM - 1)));
  float4 u;
  u.x = fmaxf(0.f, 0.9f * xv.x + 0.1f * (iv.x + bv.x));
  u.y = fmaxf(0.f, 0.9f * xv.y + 0.1f * (iv.y + bv.y));
  u.z = fmaxf(0.f, 0.9f * xv.z + 0.1f * (iv.z + bv.z));
  u.w = fmaxf(0.f, 0.9f * xv.w + 0.1f * (iv.w + bv.w));
  *(float4*)(u_f32 + e) = u;
  ushort4 ub;
  ub.x = f2bf(u.x); ub.y = f2bf(u.y); ub.z = f2bf(u.z); ub.w = f2bf(u.w);
  *(ushort4*)(u_bf16 + e) = ub;
}

// ---------------- prep_w: Wt[n][k] = signs[k]*|W[k][n]|, transposed, bf16 --
// n in [0,2048): W = r (diag zeroed);  n in [2048,2560): W = f (col n-2048).
__global__ __launch_bounds__(256) void prep_w(const float* __restrict__ r,
                                              const float* __restrict__ f,
                                              u16* __restrict__ wt) {
  __shared__ u16 ldsT[64][72];  // [n_local][k_local], stride 144B (16B aligned)
  const int k0 = blockIdx.y * 64;
  const int n0 = blockIdx.x * 64;
  const int tid = threadIdx.x;
  const int rloc = tid >> 4;        // 0..15
  const int c4 = (tid & 15) * 4;    // 0..60
#pragma unroll
  for (int rr = 0; rr < 4; ++rr) {
    const int kl = rr * 16 + rloc;
    const int k = k0 + kl;
    const float sign = (k < E_NUM) ? 1.f : -1.f;
    float4 v;
    if (n0 < N_NUM) {
      v = *(const float4*)(r + k * N_NUM + n0 + c4);
    } else {
      v = *(const float4*)(f + k * OUT_NUM + (n0 - N_NUM) + c4);
    }
    float vals[4] = {v.x, v.y, v.z, v.w};
#pragma unroll
    for (int j = 0; j < 4; ++j) {
      float val = sign * fabsf(vals[j]);
      if (n0 < N_NUM && (n0 + c4 + j) == k) val = 0.f;  // self-mask diagonal
      ldsT[c4 + j][kl] = f2bf(val);
    }
  }
  __syncthreads();
  const int nl = tid >> 2;          // 0..63
  const int kc = (tid & 3) * 16;    // 0,16,32,48
  u16* dst = wt + (n0 + nl) * N_NUM + k0 + kc;
  *(uint4*)(dst) = *(const uint4*)&ldsT[nl][kc];
  *(uint4*)(dst + 8) = *(const uint4*)&ldsT[nl][kc + 8];
}

// ---------------- gemm: C = U[4096x2048] @ Wt^T  (Wt is [2560][2048]) -----
// m97 structure: 128x128 tile, BK=64, 4 waves (2x2 of 64x64), 16x16x32 MFMA.
__global__ __launch_bounds__(256) void gemm_fused(const u16* __restrict__ U,
                                                  const u16* __restrict__ Wt,
                                                  float* __restrict__ out) {
  __shared__ u16 lA[128 * 64];
  __shared__ u16 lB[128 * 64];
  const int tid = threadIdx.x;
  const int wid = tid >> 6;
  const int lane = tid & 63;
  const int row0 = blockIdx.y * 128;
  const int col0 = blockIdx.x * 128;
  const int wr = (wid >> 1) * 64;  // wave row offset in tile
  const int wc = (wid & 1) * 64;   // wave col offset in tile

  f32x4 acc[4][4] = {};

  const int s_row = lane >> 3;        // 0..7 row within 8-row chunk
  const int s_col = (lane & 7) * 8;   // k element offset (16B per lane)

  for (int k0 = 0; k0 < N_NUM; k0 += 64) {
#pragma unroll
    for (int i = 0; i < 4; ++i) {
      const int chunk = wid * 4 + i;  // 0..15 (8 rows each)
      gload_lds16(U + (row0 + chunk * 8 + s_row) * N_NUM + k0 + s_col,
                  &lA[chunk * 512]);
    }
#pragma unroll
    for (int i = 0; i < 4; ++i) {
      const int chunk = wid * 4 + i;
      gload_lds16(Wt + (col0 + chunk * 8 + s_row) * N_NUM + k0 + s_col,
                  &lB[chunk * 512]);
    }
    __syncthreads();  // compiler drains vmcnt before s_barrier

    const int lr = lane & 15;
#pragma unroll
    for (int kk = 0; kk < 64; kk += 32) {
      const int lc = kk + (lane >> 4) * 8;
      bf16x8 af[4], bfr[4];
#pragma unroll
      for (int mi = 0; mi < 4; ++mi)
        af[mi] = *(const bf16x8*)&lA[(wr + mi * 16 + lr) * 64 + lc];
#pragma unroll
      for (int ni = 0; ni < 4; ++ni)
        bfr[ni] = *(const bf16x8*)&lB[(wc + ni * 16 + lr) * 64 + lc];
#pragma unroll
      for (int mi = 0; mi < 4; ++mi)
#pragma unroll
        for (int ni = 0; ni < 4; ++ni)
          acc[mi][ni] = __builtin_amdgcn_mfma_f32_16x16x32_bf16(
              af[mi], bfr[ni], acc[mi][ni], 0, 0, 0);
    }
    __syncthreads();
  }

  // Epilogue: C/D layout col=lane&15, row=(lane>>4)*4+q (m89/m91 verified).
  // col <  2048 -> r_out at d_out[B*OUT + row*2048 + col]
  // col >= 2048 -> f_out at d_out[row*512 + (col-2048)]
  const int orow = row0 + wr + ((lane >> 4) << 2);
  const int ocol = col0 + wc + (lane & 15);
#pragma unroll
  for (int mi = 0; mi < 4; ++mi) {
#pragma unroll
    for (int ni = 0; ni < 4; ++ni) {
      const int col = ocol + ni * 16;
#pragma unroll
      for (int q = 0; q < 4; ++q) {
        const int row = orow + mi * 16 + q;
        if (col < N_NUM)
          out[B_NUM * OUT_NUM + row * N_NUM + col] = acc[mi][ni][q];
        else
          out[row * OUT_NUM + (col - N_NUM)] = acc[mi][ni][q];
      }
    }
  }
}

extern "C" void kernel_launch(void* const* d_in, const int* in_sizes, int n_in,
                              void* d_out, int out_size, void* d_ws, size_t ws_size,
                              hipStream_t stream) {
  const float* i_ = (const float*)d_in[0];
  const float* x  = (const float*)d_in[1];
  const float* r  = (const float*)d_in[2];
  const float* f  = (const float*)d_in[3];
  const float* b  = (const float*)d_in[4];
  float* out = (float*)d_out;

  u16* U  = (u16*)d_ws;                                      // 16 MB
  u16* Wt = (u16*)((char*)d_ws + (size_t)B_NUM * N_NUM * 2); // 10 MB

  float* u_region = out + (size_t)B_NUM * OUT_NUM + (size_t)B_NUM * N_NUM;

  prep_u<<<(B_NUM * N_NUM / 4) / 256, 256, 0, stream>>>(i_, x, b, u_region, U);
  prep_w<<<dim3(NTOT / 64, N_NUM / 64), 256, 0, stream>>>(r, f, Wt);
  gemm_fused<<<dim3(NTOT / 128, B_NUM / 128), 256, 0, stream>>>(U, Wt, out);
}

// Round 2
// 204.252 us; speedup vs baseline: 1.1572x; 1.1572x over previous
//
#include <hip/hip_runtime.h>
#include <hip/hip_bf16.h>

#define B_NUM 4096
#define N_NUM 2048
#define E_NUM 1638
#define OUT_NUM 512
#define NTOT 2560   // N_NUM + OUT_NUM
#define KDIM 2048
#define NKT 32      // K tiles of 64

typedef unsigned short u16;
typedef __attribute__((ext_vector_type(8))) __bf16 bf16x8;
typedef __attribute__((ext_vector_type(4))) float f32x4;

__device__ __forceinline__ u16 f2bf(float f) {
  union { float f; unsigned u; } v; v.f = f;
  unsigned r = v.u + 0x7fffu + ((v.u >> 16) & 1u);
  return (u16)(r >> 16);
}

__device__ __forceinline__ void gload16(const u16* src, u16* dst) {
  __builtin_amdgcn_global_load_lds((__attribute__((address_space(1))) void*)src,
                                   (__attribute__((address_space(3))) void*)dst,
                                   16, 0, 0);
}

// raw barrier: no vmcnt drain (unlike __syncthreads); memory clobbers pin
// compiler-side ordering of ds/global ops across it.
#define BAR() do { asm volatile("" ::: "memory"); \
                   __builtin_amdgcn_s_barrier();  \
                   asm volatile("" ::: "memory"); } while (0)

// ---------------- prep_u: u = relu(0.9*x + 0.1*(i + b)) ----------------
__global__ __launch_bounds__(256) void prep_u(const float* __restrict__ in_i,
                                              const float* __restrict__ in_x,
                                              const float* __restrict__ bias,
                                              float* __restrict__ u_f32,
                                              u16* __restrict__ u_bf16) {
  const int t = blockIdx.x * 256 + threadIdx.x;
  const int e = t * 4;
  const float4 iv = *(const float4*)(in_i + e);
  const float4 xv = *(const float4*)(in_x + e);
  const float4 bv = *(const float4*)(bias + (e & (N_NUM - 1)));
  float4 u;
  u.x = fmaxf(0.f, 0.9f * xv.x + 0.1f * (iv.x + bv.x));
  u.y = fmaxf(0.f, 0.9f * xv.y + 0.1f * (iv.y + bv.y));
  u.z = fmaxf(0.f, 0.9f * xv.z + 0.1f * (iv.z + bv.z));
  u.w = fmaxf(0.f, 0.9f * xv.w + 0.1f * (iv.w + bv.w));
  *(float4*)(u_f32 + e) = u;
  ushort4 ub;
  ub.x = f2bf(u.x); ub.y = f2bf(u.y); ub.z = f2bf(u.z); ub.w = f2bf(u.w);
  *(ushort4*)(u_bf16 + e) = ub;
}

// ---------------- prep_w: Wt[n][k] = signs[k]*|W[k][n]|, transposed, bf16 --
__global__ __launch_bounds__(256) void prep_w(const float* __restrict__ r,
                                              const float* __restrict__ f,
                                              u16* __restrict__ wt) {
  __shared__ u16 ldsT[64][72];
  const int k0 = blockIdx.y * 64;
  const int n0 = blockIdx.x * 64;
  const int tid = threadIdx.x;
  const int rloc = tid >> 4;
  const int c4 = (tid & 15) * 4;
#pragma unroll
  for (int rr = 0; rr < 4; ++rr) {
    const int kl = rr * 16 + rloc;
    const int k = k0 + kl;
    const float sign = (k < E_NUM) ? 1.f : -1.f;
    float4 v;
    if (n0 < N_NUM) v = *(const float4*)(r + k * N_NUM + n0 + c4);
    else            v = *(const float4*)(f + k * OUT_NUM + (n0 - N_NUM) + c4);
    float vals[4] = {v.x, v.y, v.z, v.w};
#pragma unroll
    for (int j = 0; j < 4; ++j) {
      float val = sign * fabsf(vals[j]);
      if (n0 < N_NUM && (n0 + c4 + j) == k) val = 0.f;
      ldsT[c4 + j][kl] = f2bf(val);
    }
  }
  __syncthreads();
  const int nl = tid >> 2;
  const int kc = (tid & 3) * 16;
  u16* dst = wt + (n0 + nl) * KDIM + k0 + kc;
  *(uint4*)(dst) = *(const uint4*)&ldsT[nl][kc];
  *(uint4*)(dst + 8) = *(const uint4*)&ldsT[nl][kc + 8];
}

// ---------------- gemm8: deep-pipelined 256x256, BK=64, 8 waves ----------
// C = U[4096x2048] @ Wt^T (Wt [2560][2048]).  T2 swizzle + T3/T4 counted
// vmcnt + T5 setprio.  Schedule (per K-tile T, buffer c = T&1):
//   ph0: ds_read B(all 8 frags)+A(mi0-3); issue STAGE A(T+1)->buf[c^1];
//        BAR; setprio1; 32 MFMA; setprio0; BAR
//   ph1: ds_read A(mi4-7); issue STAGE B(T+2)->buf[c];
//        BAR; setprio1; 32 MFMA; setprio0; vmcnt(4); BAR
// Safety: every ds_read is consumed (lgkm-drained) before the MFMA that
// precedes the phase-end barrier, so a stage issued in a later phase can
// never clobber an un-executed read.  vmcnt(4) leaves exactly B(T+2) (4
// loads) in flight; A(T+1)/B(T+1) proven landed before T+1's reads.
// Swizzle: physical colbyte = logical ^ ((row&7)<<4), applied on BOTH the
// pre-swizzled global source (linear LDS dest, rule 21) and ds_read addr.
__global__ __launch_bounds__(512, 2) void gemm8(const u16* __restrict__ U,
                                                const u16* __restrict__ Wt,
                                                float* __restrict__ out) {
  __shared__ u16 lds[2][2][256 * 64];  // [dbuf][0=A,1=B], 128 KiB total
  const int t = threadIdx.x;
  const int w = t >> 6, lane = t & 63;
  const int lr = lane & 15, lg = lane >> 4;
  const int wm = w >> 2, wn = w & 3;       // 2x4 wave grid, wave tile 128x64
  const int row0 = blockIdx.y * 256;
  const int col0 = blockIdx.x * 256;

  // staging constants: thread t covers phys bytes (i*64 + t/8)*128 + (t&7)*16
  const int srow = t >> 3;                              // 0..63
  const int koff = 8 * ((t & 7) ^ (srow & 7));          // pre-swizzled k source
  const u16* aS = U  + (row0 + srow) * KDIM + koff;
  const u16* bS = Wt + (col0 + srow) * KDIM + koff;
  const int stBase = (w * 8) * 64;                      // wave-uniform LDS base

  // fragment-read constants
  const int arow = wm * 128 + lr;
  const int brow = wn * 64 + lr;
  const int xs = (lr & 7) << 4;
  const int ca0 = ((lg * 16) ^ xs) >> 1;        // kk=0 swizzled col (u16)
  const int ca1 = ((64 + lg * 16) ^ xs) >> 1;   // kk=1

  f32x4 acc[8][4] = {};

#define STAGE_A(c, kt) { const int k0_ = (kt) * 64;                         \
  _Pragma("unroll") for (int i_ = 0; i_ < 4; ++i_)                          \
    gload16(aS + i_ * 64 * KDIM + k0_, &lds[c][0][i_ * 4096 + stBase]); }
#define STAGE_B(c, kt) { const int k0_ = (kt) * 64;                         \
  _Pragma("unroll") for (int i_ = 0; i_ < 4; ++i_)                          \
    gload16(bS + i_ * 64 * KDIM + k0_, &lds[c][1][i_ * 4096 + stBase]); }

  // prologue: queue = [B(0) x4, A(0) x4, B(1) x4]; retire first 8
  STAGE_B(0, 0);
  STAGE_A(0, 0);
  STAGE_B(1, 1);
  asm volatile("s_waitcnt vmcnt(4)" ::: "memory");
  __builtin_amdgcn_sched_barrier(0);
  BAR();

  for (int T = 0; T < NKT; ++T) {
    const int c = T & 1;
    const u16* lA = lds[c][0];
    const u16* lB = lds[c][1];
    bf16x8 bf[4][2], af[4][2];
    // ---- phase 0: B all + A rows 0-63 of wave half ----
#pragma unroll
    for (int ni = 0; ni < 4; ++ni) {
      bf[ni][0] = *(const bf16x8*)&lB[(brow + ni * 16) * 64 + ca0];
      bf[ni][1] = *(const bf16x8*)&lB[(brow + ni * 16) * 64 + ca1];
    }
#pragma unroll
    for (int mi = 0; mi < 4; ++mi) {
      af[mi][0] = *(const bf16x8*)&lA[(arow + mi * 16) * 64 + ca0];
      af[mi][1] = *(const bf16x8*)&lA[(arow + mi * 16) * 64 + ca1];
    }
    { const int tn = (T + 1 < NKT) ? T + 1 : NKT - 1;  // clamp keeps vmcnt exact
      STAGE_A(c ^ 1, tn); }
    BAR();
    __builtin_amdgcn_s_setprio(1);
#pragma unroll
    for (int mi = 0; mi < 4; ++mi)
#pragma unroll
      for (int ni = 0; ni < 4; ++ni) {
        acc[mi][ni] = __builtin_amdgcn_mfma_f32_16x16x32_bf16(af[mi][0], bf[ni][0], acc[mi][ni], 0, 0, 0);
        acc[mi][ni] = __builtin_amdgcn_mfma_f32_16x16x32_bf16(af[mi][1], bf[ni][1], acc[mi][ni], 0, 0, 0);
      }
    __builtin_amdgcn_s_setprio(0);
    BAR();
    // ---- phase 1: A rows 64-127 of wave half ----
#pragma unroll
    for (int mi = 0; mi < 4; ++mi) {
      af[mi][0] = *(const bf16x8*)&lA[(arow + 64 + mi * 16) * 64 + ca0];
      af[mi][1] = *(const bf16x8*)&lA[(arow + 64 + mi * 16) * 64 + ca1];
    }
    { const int tn = (T + 2 < NKT) ? T + 2 : NKT - 1;
      STAGE_B(c, tn); }
    BAR();
    __builtin_amdgcn_s_setprio(1);
#pragma unroll
    for (int mi = 0; mi < 4; ++mi)
#pragma unroll
      for (int ni = 0; ni < 4; ++ni) {
        acc[4 + mi][ni] = __builtin_amdgcn_mfma_f32_16x16x32_bf16(af[mi][0], bf[ni][0], acc[4 + mi][ni], 0, 0, 0);
        acc[4 + mi][ni] = __builtin_amdgcn_mfma_f32_16x16x32_bf16(af[mi][1], bf[ni][1], acc[4 + mi][ni], 0, 0, 0);
      }
    __builtin_amdgcn_s_setprio(0);
    asm volatile("s_waitcnt vmcnt(4)" ::: "memory");
    __builtin_amdgcn_sched_barrier(0);
    BAR();
  }
  asm volatile("s_waitcnt vmcnt(0)" ::: "memory");  // drain DMA before endpgm

  // epilogue: C/D map col=lane&15, row=(lane>>4)*4+q
  const int orow = row0 + wm * 128 + lg * 4;
  const int ocol = col0 + wn * 64 + lr;
  if (col0 < N_NUM) {           // whole tile -> r_out (2048 % 256 == 0)
    float* ro = out + B_NUM * OUT_NUM;
#pragma unroll
    for (int mi = 0; mi < 8; ++mi)
#pragma unroll
      for (int ni = 0; ni < 4; ++ni)
#pragma unroll
        for (int q = 0; q < 4; ++q)
          ro[(orow + mi * 16 + q) * N_NUM + ocol + ni * 16] = acc[mi][ni][q];
  } else {                      // whole tile -> f_out
#pragma unroll
    for (int mi = 0; mi < 8; ++mi)
#pragma unroll
      for (int ni = 0; ni < 4; ++ni)
#pragma unroll
        for (int q = 0; q < 4; ++q)
          out[(orow + mi * 16 + q) * OUT_NUM + (ocol - N_NUM) + ni * 16] = acc[mi][ni][q];
  }
#undef STAGE_A
#undef STAGE_B
}

extern "C" void kernel_launch(void* const* d_in, const int* in_sizes, int n_in,
                              void* d_out, int out_size, void* d_ws, size_t ws_size,
                              hipStream_t stream) {
  const float* i_ = (const float*)d_in[0];
  const float* x  = (const float*)d_in[1];
  const float* r  = (const float*)d_in[2];
  const float* f  = (const float*)d_in[3];
  const float* b  = (const float*)d_in[4];
  float* out = (float*)d_out;

  u16* U  = (u16*)d_ws;                                      // 16 MB
  u16* Wt = (u16*)((char*)d_ws + (size_t)B_NUM * KDIM * 2);  // 10 MB

  float* u_region = out + (size_t)B_NUM * OUT_NUM + (size_t)B_NUM * N_NUM;

  prep_u<<<(B_NUM * N_NUM / 4) / 256, 256, 0, stream>>>(i_, x, b, u_region, U);
  prep_w<<<dim3(NTOT / 64, N_NUM / 64), 256, 0, stream>>>(r, f, Wt);
  gemm8<<<dim3(NTOT / 256, B_NUM / 256), 512, 0, stream>>>(U, Wt, out);
}

// Round 3
// 198.711 us; speedup vs baseline: 1.1895x; 1.0279x over previous
//
#include <hip/hip_runtime.h>
#include <hip/hip_bf16.h>

#define B_NUM 4096
#define N_NUM 2048
#define E_NUM 1638
#define OUT_NUM 512
#define NTOT 2560   // N_NUM + OUT_NUM
#define KDIM 2048
#define NKT 32      // K tiles of 64

typedef unsigned short u16;
typedef __attribute__((ext_vector_type(8))) __bf16 bf16x8;
typedef __attribute__((ext_vector_type(4))) float f32x4;

__device__ __forceinline__ u16 f2bf(float f) {
  union { float f; unsigned u; } v; v.f = f;
  unsigned r = v.u + 0x7fffu + ((v.u >> 16) & 1u);
  return (u16)(r >> 16);
}

__device__ __forceinline__ void gload16(const u16* src, u16* dst) {
  __builtin_amdgcn_global_load_lds((__attribute__((address_space(1))) void*)src,
                                   (__attribute__((address_space(3))) void*)dst,
                                   16, 0, 0);
}

// raw barrier: no vmcnt drain (unlike __syncthreads); memory clobbers pin
// compiler-side ordering of ds/global ops across it.
#define BAR() do { asm volatile("" ::: "memory"); \
                   __builtin_amdgcn_s_barrier();  \
                   asm volatile("" ::: "memory"); } while (0)

// ---------------- prep_u: u = relu(0.9*x + 0.1*(i + b)) ----------------
__global__ __launch_bounds__(256) void prep_u(const float* __restrict__ in_i,
                                              const float* __restrict__ in_x,
                                              const float* __restrict__ bias,
                                              float* __restrict__ u_f32,
                                              u16* __restrict__ u_bf16) {
  const int t = blockIdx.x * 256 + threadIdx.x;
  const int e = t * 4;
  const float4 iv = *(const float4*)(in_i + e);
  const float4 xv = *(const float4*)(in_x + e);
  const float4 bv = *(const float4*)(bias + (e & (N_NUM - 1)));
  float4 u;
  u.x = fmaxf(0.f, 0.9f * xv.x + 0.1f * (iv.x + bv.x));
  u.y = fmaxf(0.f, 0.9f * xv.y + 0.1f * (iv.y + bv.y));
  u.z = fmaxf(0.f, 0.9f * xv.z + 0.1f * (iv.z + bv.z));
  u.w = fmaxf(0.f, 0.9f * xv.w + 0.1f * (iv.w + bv.w));
  *(float4*)(u_f32 + e) = u;
  ushort4 ub;
  ub.x = f2bf(u.x); ub.y = f2bf(u.y); ub.z = f2bf(u.z); ub.w = f2bf(u.w);
  *(ushort4*)(u_bf16 + e) = ub;
}

// ---------------- prep_w: Wt[n][k] = signs[k]*|W[k][n]|, transposed, bf16 --
__global__ __launch_bounds__(256) void prep_w(const float* __restrict__ r,
                                              const float* __restrict__ f,
                                              u16* __restrict__ wt) {
  __shared__ u16 ldsT[64][72];
  const int k0 = blockIdx.y * 64;
  const int n0 = blockIdx.x * 64;
  const int tid = threadIdx.x;
  const int rloc = tid >> 4;
  const int c4 = (tid & 15) * 4;
#pragma unroll
  for (int rr = 0; rr < 4; ++rr) {
    const int kl = rr * 16 + rloc;
    const int k = k0 + kl;
    const float sign = (k < E_NUM) ? 1.f : -1.f;
    float4 v;
    if (n0 < N_NUM) v = *(const float4*)(r + k * N_NUM + n0 + c4);
    else            v = *(const float4*)(f + k * OUT_NUM + (n0 - N_NUM) + c4);
    float vals[4] = {v.x, v.y, v.z, v.w};
#pragma unroll
    for (int j = 0; j < 4; ++j) {
      float val = sign * fabsf(vals[j]);
      if (n0 < N_NUM && (n0 + c4 + j) == k) val = 0.f;
      ldsT[c4 + j][kl] = f2bf(val);
    }
  }
  __syncthreads();
  const int nl = tid >> 2;
  const int kc = (tid & 3) * 16;
  u16* dst = wt + (n0 + nl) * KDIM + k0 + kc;
  *(uint4*)(dst) = *(const uint4*)&ldsT[nl][kc];
  *(uint4*)(dst + 8) = *(const uint4*)&ldsT[nl][kc + 8];
}

// ---------------- gemm4: 128x128 tile, BK=64, 4 waves, 2 blocks/CU -------
// C = U[4096x2048] @ Wt^T (Wt [2560][2048]).  R2's proven schedule scaled
// to 128^2 for grid=640 (fill 0.625 -> ~0.95) + 2-block/CU co-residency.
// Per K-tile T, buffer c = T&1:
//   ph0: ds_read B all 8 frags + A(mi0-1) 4 frags; issue STAGE A(T+1)->c^1;
//        BAR; setprio1; 16 MFMA; setprio0; BAR
//   ph1: ds_read A(mi2-3) 4 frags; issue STAGE B(T+2)->buf[c] (B-reads all
//        retired at ph0-end BAR); BAR; setprio1; 16 MFMA; setprio0;
//        vmcnt(4); BAR     // leaves exactly B(T+2) in flight
// Swizzle (T2): phys colbyte = logical ^ ((row&7)<<4) on BOTH the
// pre-swizzled global source (linear LDS dest) and the ds_read address.
__global__ __launch_bounds__(256, 2) void gemm4(const u16* __restrict__ U,
                                                const u16* __restrict__ Wt,
                                                float* __restrict__ out) {
  __shared__ u16 lds[2][2][128 * 64];  // [dbuf][0=A,1=B], 64 KiB total
  const int t = threadIdx.x;
  const int w = t >> 6, lane = t & 63;
  const int lr = lane & 15, lg = lane >> 4;
  const int wm = w >> 1, wn = w & 1;       // 2x2 wave grid, wave tile 64x64
  const int row0 = blockIdx.y * 128;
  const int col0 = blockIdx.x * 128;

  // staging: thread t covers phys LDS u16 offset i*2048 + t*8
  //   -> row i*32 + (t>>3), phys col-u16 (t&7)*8
  const int srow = t >> 3;                              // 0..31
  const int koff = 8 * ((t & 7) ^ (srow & 7));          // pre-swizzled src col
  const u16* aS = U  + (row0 + srow) * KDIM + koff;
  const u16* bS = Wt + (col0 + srow) * KDIM + koff;
  const int stBase = w * 512;                           // wave-uniform base

  // fragment-read constants
  const int arow = wm * 64 + lr;
  const int brow = wn * 64 + lr;
  const int xs = (lr & 7) << 4;
  const int ca0 = ((lg * 16) ^ xs) >> 1;        // k-slice 0, swizzled (u16)
  const int ca1 = ((64 + lg * 16) ^ xs) >> 1;   // k-slice 1

  f32x4 acc[4][4] = {};

#define STAGE_A(c, kt) { const int k0_ = (kt) * 64;                         \
  _Pragma("unroll") for (int i_ = 0; i_ < 4; ++i_)                          \
    gload16(aS + i_ * 32 * KDIM + k0_, &lds[c][0][i_ * 2048 + stBase]); }
#define STAGE_B(c, kt) { const int k0_ = (kt) * 64;                         \
  _Pragma("unroll") for (int i_ = 0; i_ < 4; ++i_)                          \
    gload16(bS + i_ * 32 * KDIM + k0_, &lds[c][1][i_ * 2048 + stBase]); }

  // prologue: queue = [B(0) x4, A(0) x4, B(1) x4]; retire first 8
  STAGE_B(0, 0);
  STAGE_A(0, 0);
  STAGE_B(1, 1);
  asm volatile("s_waitcnt vmcnt(4)" ::: "memory");
  __builtin_amdgcn_sched_barrier(0);
  BAR();

  for (int T = 0; T < NKT; ++T) {
    const int c = T & 1;
    const u16* lA = lds[c][0];
    const u16* lB = lds[c][1];
    bf16x8 bf[4][2], af[2][2];
    // ---- phase 0: all B frags + A rows mi 0-1 ----
#pragma unroll
    for (int ni = 0; ni < 4; ++ni) {
      bf[ni][0] = *(const bf16x8*)&lB[(brow + ni * 16) * 64 + ca0];
      bf[ni][1] = *(const bf16x8*)&lB[(brow + ni * 16) * 64 + ca1];
    }
#pragma unroll
    for (int mi = 0; mi < 2; ++mi) {
      af[mi][0] = *(const bf16x8*)&lA[(arow + mi * 16) * 64 + ca0];
      af[mi][1] = *(const bf16x8*)&lA[(arow + mi * 16) * 64 + ca1];
    }
    { const int tn = (T + 1 < NKT) ? T + 1 : NKT - 1;  // clamp keeps vmcnt exact
      STAGE_A(c ^ 1, tn); }
    BAR();
    __builtin_amdgcn_s_setprio(1);
#pragma unroll
    for (int mi = 0; mi < 2; ++mi)
#pragma unroll
      for (int ni = 0; ni < 4; ++ni) {
        acc[mi][ni] = __builtin_amdgcn_mfma_f32_16x16x32_bf16(af[mi][0], bf[ni][0], acc[mi][ni], 0, 0, 0);
        acc[mi][ni] = __builtin_amdgcn_mfma_f32_16x16x32_bf16(af[mi][1], bf[ni][1], acc[mi][ni], 0, 0, 0);
      }
    __builtin_amdgcn_s_setprio(0);
    BAR();
    // ---- phase 1: A rows mi 2-3 ----
#pragma unroll
    for (int mi = 0; mi < 2; ++mi) {
      af[mi][0] = *(const bf16x8*)&lA[(arow + 32 + mi * 16) * 64 + ca0];
      af[mi][1] = *(const bf16x8*)&lA[(arow + 32 + mi * 16) * 64 + ca1];
    }
    { const int tn = (T + 2 < NKT) ? T + 2 : NKT - 1;
      STAGE_B(c, tn); }
    BAR();
    __builtin_amdgcn_s_setprio(1);
#pragma unroll
    for (int mi = 0; mi < 2; ++mi)
#pragma unroll
      for (int ni = 0; ni < 4; ++ni) {
        acc[2 + mi][ni] = __builtin_amdgcn_mfma_f32_16x16x32_bf16(af[mi][0], bf[ni][0], acc[2 + mi][ni], 0, 0, 0);
        acc[2 + mi][ni] = __builtin_amdgcn_mfma_f32_16x16x32_bf16(af[mi][1], bf[ni][1], acc[2 + mi][ni], 0, 0, 0);
      }
    __builtin_amdgcn_s_setprio(0);
    asm volatile("s_waitcnt vmcnt(4)" ::: "memory");
    __builtin_amdgcn_sched_barrier(0);
    BAR();
  }
  asm volatile("s_waitcnt vmcnt(0)" ::: "memory");  // drain DMA before endpgm

  // epilogue: C/D map col=lane&15, row=(lane>>4)*4+q
  const int orow = row0 + wm * 64 + lg * 4;
  const int ocol = col0 + wn * 64 + lr;
  if (col0 < N_NUM) {           // whole tile -> r_out (2048 % 128 == 0)
    float* ro = out + B_NUM * OUT_NUM;
#pragma unroll
    for (int mi = 0; mi < 4; ++mi)
#pragma unroll
      for (int ni = 0; ni < 4; ++ni)
#pragma unroll
        for (int q = 0; q < 4; ++q)
          ro[(orow + mi * 16 + q) * N_NUM + ocol + ni * 16] = acc[mi][ni][q];
  } else {                      // whole tile -> f_out
#pragma unroll
    for (int mi = 0; mi < 4; ++mi)
#pragma unroll
      for (int ni = 0; ni < 4; ++ni)
#pragma unroll
        for (int q = 0; q < 4; ++q)
          out[(orow + mi * 16 + q) * OUT_NUM + (ocol - N_NUM) + ni * 16] = acc[mi][ni][q];
  }
#undef STAGE_A
#undef STAGE_B
}

extern "C" void kernel_launch(void* const* d_in, const int* in_sizes, int n_in,
                              void* d_out, int out_size, void* d_ws, size_t ws_size,
                              hipStream_t stream) {
  const float* i_ = (const float*)d_in[0];
  const float* x  = (const float*)d_in[1];
  const float* r  = (const float*)d_in[2];
  const float* f  = (const float*)d_in[3];
  const float* b  = (const float*)d_in[4];
  float* out = (float*)d_out;

  u16* U  = (u16*)d_ws;                                      // 16 MB
  u16* Wt = (u16*)((char*)d_ws + (size_t)B_NUM * KDIM * 2);  // 10 MB

  float* u_region = out + (size_t)B_NUM * OUT_NUM + (size_t)B_NUM * N_NUM;

  prep_u<<<(B_NUM * N_NUM / 4) / 256, 256, 0, stream>>>(i_, x, b, u_region, U);
  prep_w<<<dim3(NTOT / 64, N_NUM / 64), 256, 0, stream>>>(r, f, Wt);
  gemm4<<<dim3(NTOT / 128, B_NUM / 128), 256, 0, stream>>>(U, Wt, out);
}